// Round 1
// baseline (210.445 us; speedup 1.0000x reference)
//
#include <hip/hip_runtime.h>

typedef unsigned short u16;
typedef __bf16 bf16x8 __attribute__((ext_vector_type(8)));
typedef float f32x4 __attribute__((ext_vector_type(4)));

#define DEV static __device__ __forceinline__

DEV float bf2f(u16 u) { unsigned x = ((unsigned)u) << 16; return __builtin_bit_cast(float, x); }
DEV u16 f2bf(float f) {
  unsigned u = __builtin_bit_cast(unsigned, f);
  u += 0x7FFFu + ((u >> 16) & 1u);
  return (u16)(u >> 16);
}

#define GLD_LDS16(gp, lp)                                                    \
  __builtin_amdgcn_global_load_lds(                                          \
      (__attribute__((address_space(1))) void*)(void*)(gp),                  \
      (__attribute__((address_space(3))) void*)(lp), 16, 0, 0)

// ---------------------------------------------------------------------------
// Transpose + fp32->bf16 convert:  W[K][Ncols] -> Wt[Ncols][K]
// ---------------------------------------------------------------------------
__global__ void transpose_bf16(const float* __restrict__ W, u16* __restrict__ Wt,
                               int K, int Ncols) {
  __shared__ float t[32][33];
  const int tx = threadIdx.x & 31, ty = threadIdx.x >> 5;  // 32 x 8
  const int n0 = blockIdx.x * 32, k0 = blockIdx.y * 32;
#pragma unroll
  for (int i = 0; i < 4; ++i)
    t[ty + i * 8][tx] = W[(size_t)(k0 + ty + i * 8) * Ncols + n0 + tx];
  __syncthreads();
#pragma unroll
  for (int i = 0; i < 4; ++i)
    Wt[(size_t)(n0 + ty + i * 8) * K + k0 + tx] = f2bf(t[tx][ty + i * 8]);
}

// ---------------------------------------------------------------------------
// GEMM, 128x128 tile, BK=32, 4 waves (2x2), mfma_f32_16x16x32_bf16.
// MODE 0: A = fp32 x [32768][512] (reg-staged, converted), B = Wqkv_t bf16
//         [1536][512]; epilogue: elu+1 on cols<1024; out -> q/k/v bf16 bufs.
// MODE 1: A = attn bf16 [32768][512] (global_load_lds), B = Wout_t bf16
//         [512][512]; epilogue: + bias; out -> fp32 Cf.
// ---------------------------------------------------------------------------
template <int MODE>
__global__ __launch_bounds__(256, 2) void gemm_kernel(
    const void* __restrict__ Av, const u16* __restrict__ Bt,
    u16* __restrict__ qb, u16* __restrict__ kb, u16* __restrict__ vb,
    float* __restrict__ Cf, const float* __restrict__ bias) {
  constexpr int BK = 32;
  constexpr int K = 512;
  __shared__ __align__(16) u16 As[128 * BK];
  __shared__ __align__(16) u16 Bs[128 * BK];
  const int tid = threadIdx.x;
  const int lane = tid & 63;
  const int wid = tid >> 6;
  const int wr = wid >> 1, wc = wid & 1;
  const int rowBase = blockIdx.y * 128;
  const int colBase = blockIdx.x * 128;

  const float* Af = (const float*)Av;
  const u16* Ab = (const u16*)Av;

  f32x4 zv = {0.f, 0.f, 0.f, 0.f};
  f32x4 acc[4][4];
#pragma unroll
  for (int m = 0; m < 4; ++m)
#pragma unroll
    for (int n = 0; n < 4; ++n) acc[m][n] = zv;

  for (int k0 = 0; k0 < K; k0 += BK) {
    // ---- stage A tile [128][32]
    if (MODE == 0) {
      const int r = tid >> 1, c0 = (tid & 1) * 16;
      const float4* src = (const float4*)(Af + (size_t)(rowBase + r) * K + k0 + c0);
      float4 f0 = src[0], f1 = src[1], f2 = src[2], f3 = src[3];
      unsigned pw[8];
      pw[0] = (unsigned)f2bf(f0.x) | ((unsigned)f2bf(f0.y) << 16);
      pw[1] = (unsigned)f2bf(f0.z) | ((unsigned)f2bf(f0.w) << 16);
      pw[2] = (unsigned)f2bf(f1.x) | ((unsigned)f2bf(f1.y) << 16);
      pw[3] = (unsigned)f2bf(f1.z) | ((unsigned)f2bf(f1.w) << 16);
      pw[4] = (unsigned)f2bf(f2.x) | ((unsigned)f2bf(f2.y) << 16);
      pw[5] = (unsigned)f2bf(f2.z) | ((unsigned)f2bf(f2.w) << 16);
      pw[6] = (unsigned)f2bf(f3.x) | ((unsigned)f2bf(f3.y) << 16);
      pw[7] = (unsigned)f2bf(f3.z) | ((unsigned)f2bf(f3.w) << 16);
      *(uint4*)&As[r * BK + c0] = make_uint4(pw[0], pw[1], pw[2], pw[3]);
      *(uint4*)&As[r * BK + c0 + 8] = make_uint4(pw[4], pw[5], pw[6], pw[7]);
    } else {
#pragma unroll
      for (int rr = 0; rr < 2; ++rr) {
        int idx8 = rr * 256 + tid;
        int r = idx8 >> 2, c = (idx8 & 3) * 8;
        GLD_LDS16(Ab + (size_t)(rowBase + r) * K + k0 + c,
                  &As[(rr * 256 + wid * 64) * 8]);
      }
    }
    // ---- stage B tile [128][32] (always bf16)
#pragma unroll
    for (int rr = 0; rr < 2; ++rr) {
      int idx8 = rr * 256 + tid;
      int r = idx8 >> 2, c = (idx8 & 3) * 8;
      GLD_LDS16(Bt + (size_t)(colBase + r) * K + k0 + c,
                &Bs[(rr * 256 + wid * 64) * 8]);
    }
    __syncthreads();

    bf16x8 af[4], bfr[4];
#pragma unroll
    for (int m = 0; m < 4; ++m)
      af[m] = *(const bf16x8*)&As[(wr * 64 + m * 16 + (lane & 15)) * BK + (lane >> 4) * 8];
#pragma unroll
    for (int n = 0; n < 4; ++n)
      bfr[n] = *(const bf16x8*)&Bs[(wc * 64 + n * 16 + (lane & 15)) * BK + (lane >> 4) * 8];
#pragma unroll
    for (int m = 0; m < 4; ++m)
#pragma unroll
      for (int n = 0; n < 4; ++n)
        acc[m][n] = __builtin_amdgcn_mfma_f32_16x16x32_bf16(af[m], bfr[n], acc[m][n], 0, 0, 0);
    __syncthreads();
  }

  // ---- epilogue
#pragma unroll
  for (int m = 0; m < 4; ++m) {
#pragma unroll
    for (int n = 0; n < 4; ++n) {
      const int col = colBase + wc * 64 + n * 16 + (lane & 15);
#pragma unroll
      for (int r = 0; r < 4; ++r) {
        const int row = rowBase + wr * 64 + m * 16 + (lane >> 4) * 4 + r;
        float v = acc[m][n][r];
        if (MODE == 0) {
          if (col < 1024) v = (v > 0.f) ? v + 1.f : __expf(v);  // elu(v)+1
          u16* dst;
          int c2;
          if (col < 512) {
            dst = qb; c2 = col;
          } else if (col < 1024) {
            dst = kb; c2 = col - 512;
          } else {
            dst = vb; c2 = col - 1024;
          }
          dst[(size_t)row * 512 + c2] = f2bf(v);
        } else {
          Cf[(size_t)row * 512 + col] = v + bias[col];
        }
      }
    }
  }
}

// ---------------------------------------------------------------------------
// kv partials: per (bh, chunk of 512 rows), acc[d][e] += k[n][d]*v[n][e],
// ksum[d] += k[n][d].  Output part[bh][chunk][64][80] (col 64 = ksum).
// ---------------------------------------------------------------------------
__global__ __launch_bounds__(256, 2) void kv_partial_kernel(
    const u16* __restrict__ kb, const u16* __restrict__ vb,
    float* __restrict__ part) {
  __shared__ float kf[128][64];
  __shared__ float vf[128][64];
  const int tid = threadIdx.x;
  const int chunk = blockIdx.x;  // 0..15 (512 rows each)
  const int bh = blockIdx.y;     // 0..31
  const int b = bh >> 3, h = bh & 7;
  const size_t rb = (size_t)b * 8192;
  const int hc = h * 64;
  const int dg = tid >> 4, eg = tid & 15;

  float acc[4][4] = {};
  float ks[4] = {};

  for (int st = 0; st < 4; ++st) {
    const int n0 = chunk * 512 + st * 128;
#pragma unroll
    for (int it = 0; it < 4; ++it) {
      int idx8 = it * 256 + tid;
      int r = idx8 >> 3, c = (idx8 & 7) * 8;
      uint4 kraw = *(const uint4*)(kb + (rb + n0 + r) * 512 + hc + c);
      uint4 vraw = *(const uint4*)(vb + (rb + n0 + r) * 512 + hc + c);
      unsigned kw[4] = {kraw.x, kraw.y, kraw.z, kraw.w};
      unsigned vw[4] = {vraw.x, vraw.y, vraw.z, vraw.w};
#pragma unroll
      for (int j = 0; j < 4; ++j) {
        kf[r][c + 2 * j] = bf2f((u16)(kw[j] & 0xFFFF));
        kf[r][c + 2 * j + 1] = bf2f((u16)(kw[j] >> 16));
        vf[r][c + 2 * j] = bf2f((u16)(vw[j] & 0xFFFF));
        vf[r][c + 2 * j + 1] = bf2f((u16)(vw[j] >> 16));
      }
    }
    __syncthreads();
#pragma unroll 4
    for (int n = 0; n < 128; ++n) {
      float4 kk = *(const float4*)&kf[n][dg * 4];
      float4 vv = *(const float4*)&vf[n][eg * 4];
      float ka[4] = {kk.x, kk.y, kk.z, kk.w};
      float va[4] = {vv.x, vv.y, vv.z, vv.w};
#pragma unroll
      for (int i = 0; i < 4; ++i)
#pragma unroll
        for (int j = 0; j < 4; ++j) acc[i][j] += ka[i] * va[j];
      if (eg == 0) {
#pragma unroll
        for (int i = 0; i < 4; ++i) ks[i] += ka[i];
      }
    }
    __syncthreads();
  }

  float* p = part + ((size_t)bh * 16 + chunk) * (64 * 80);
#pragma unroll
  for (int i = 0; i < 4; ++i) {
#pragma unroll
    for (int j = 0; j < 4; ++j) p[(dg * 4 + i) * 80 + eg * 4 + j] = acc[i][j];
    if (eg == 0) p[(dg * 4 + i) * 80 + 64] = ks[i];
  }
}

// ---------------------------------------------------------------------------
// Reduce partials over chunks -> kv_ext[bh][64][80]; cols 65..79 zeroed.
// ---------------------------------------------------------------------------
__global__ void kv_reduce_kernel(const float* __restrict__ part,
                                 float* __restrict__ kv_ext) {
  const int idx = blockIdx.x * 256 + threadIdx.x;  // 32*5120 total
  const int bh = idx / 5120;
  const int de = idx % 5120;
  const int e = de % 80;
  float s = 0.f;
  if (e <= 64) {
    for (int c = 0; c < 16; ++c) s += part[((size_t)bh * 16 + c) * 5120 + de];
  }
  kv_ext[idx] = s;
}

// ---------------------------------------------------------------------------
// attn[n][h*64+e] = (sum_d q[n][d]*kv[d][e]) / (sum_d q[n][d]*ksum[d] + 1e-6)
// kv_ext col 64 = ksum -> denominator comes from a 5th MFMA e-block.
// ---------------------------------------------------------------------------
__global__ __launch_bounds__(256, 2) void attn_kernel(
    const u16* __restrict__ qb, const float* __restrict__ kv_ext,
    u16* __restrict__ attn) {
  __shared__ __align__(16) float kvs[64 * 80];   // 20 KB
  __shared__ __align__(16) u16 qs[4][64 * 64];   // 32 KB
  const int tid = threadIdx.x, lane = tid & 63, wid = tid >> 6;
  const int nchunk = blockIdx.x, bh = blockIdx.y;
  const int b = bh >> 3, h = bh & 7;

#pragma unroll
  for (int i = 0; i < 20; ++i)
    kvs[i * 256 + tid] = kv_ext[(size_t)bh * 5120 + i * 256 + tid];
  __syncthreads();

  // B fragments: B[d][e] = kvs[d*80+e], 5 e-blocks x 2 k-steps (one-time)
  bf16x8 bfr[5][2];
#pragma unroll
  for (int eb = 0; eb < 5; ++eb)
#pragma unroll
    for (int ksi = 0; ksi < 2; ++ksi) {
      unsigned pw[4];
#pragma unroll
      for (int jj = 0; jj < 4; ++jj) {
        int d0 = ksi * 32 + (lane >> 4) * 8 + 2 * jj;
        int e = eb * 16 + (lane & 15);
        unsigned lo = f2bf(kvs[d0 * 80 + e]);
        unsigned hi = f2bf(kvs[(d0 + 1) * 80 + e]);
        pw[jj] = lo | (hi << 16);
      }
      uint4 u = make_uint4(pw[0], pw[1], pw[2], pw[3]);
      bfr[eb][ksi] = __builtin_bit_cast(bf16x8, u);
    }

  // stage this wave's 64 q rows
  const size_t row0 = (size_t)b * 8192 + (size_t)nchunk * 256 + wid * 64;
#pragma unroll
  for (int it = 0; it < 8; ++it) {
    int idx8 = it * 64 + lane;
    int r = idx8 >> 3, c = (idx8 & 7) * 8;
    GLD_LDS16(qb + (row0 + r) * 512 + h * 64 + c, &qs[wid][it * 512]);
  }
  asm volatile("s_waitcnt vmcnt(0)" ::: "memory");

  f32x4 zv = {0.f, 0.f, 0.f, 0.f};
  f32x4 acc[4][5];
#pragma unroll
  for (int m = 0; m < 4; ++m)
#pragma unroll
    for (int eb = 0; eb < 5; ++eb) acc[m][eb] = zv;

#pragma unroll
  for (int m = 0; m < 4; ++m)
#pragma unroll
    for (int ksi = 0; ksi < 2; ++ksi) {
      bf16x8 af = *(const bf16x8*)&qs[wid][(m * 16 + (lane & 15)) * 64 + ksi * 32 + (lane >> 4) * 8];
#pragma unroll
      for (int eb = 0; eb < 5; ++eb)
        acc[m][eb] = __builtin_amdgcn_mfma_f32_16x16x32_bf16(af, bfr[eb][ksi], acc[m][eb], 0, 0, 0);
    }

#pragma unroll
  for (int m = 0; m < 4; ++m) {
    float zr[4];
#pragma unroll
    for (int r = 0; r < 4; ++r) {
      float den = __shfl(acc[m][4][r], lane & ~15, 64);
      zr[r] = 1.f / (den + 1e-6f);
    }
#pragma unroll
    for (int eb = 0; eb < 4; ++eb)
#pragma unroll
      for (int r = 0; r < 4; ++r) {
        size_t row = row0 + m * 16 + (lane >> 4) * 4 + r;
        int col = h * 64 + eb * 16 + (lane & 15);
        attn[row * 512 + col] = f2bf(acc[m][eb][r] * zr[r]);
      }
  }
}

// ---------------------------------------------------------------------------
extern "C" void kernel_launch(void* const* d_in, const int* in_sizes, int n_in,
                              void* d_out, int out_size, void* d_ws, size_t ws_size,
                              hipStream_t stream) {
  const float* x = (const float*)d_in[0];
  const float* Wqkv = (const float*)d_in[1];
  const float* Wout = (const float*)d_in[2];
  const float* bout = (const float*)d_in[3];
  float* out = (float*)d_out;

  char* ws = (char*)d_ws;
  u16* qb = (u16*)ws;        ws += (size_t)32768 * 512 * 2;
  u16* kb = (u16*)ws;        ws += (size_t)32768 * 512 * 2;
  u16* vb = (u16*)ws;        ws += (size_t)32768 * 512 * 2;  // reused as attn
  u16* wqkv_t = (u16*)ws;    ws += (size_t)1536 * 512 * 2;
  u16* wout_t = (u16*)ws;    ws += (size_t)512 * 512 * 2;
  float* kv_ext = (float*)ws; ws += (size_t)32 * 64 * 80 * 4;
  float* part = (float*)ws;   ws += (size_t)32 * 16 * 64 * 80 * 4;

  transpose_bf16<<<dim3(1536 / 32, 512 / 32), 256, 0, stream>>>(Wqkv, wqkv_t, 512, 1536);
  transpose_bf16<<<dim3(512 / 32, 512 / 32), 256, 0, stream>>>(Wout, wout_t, 512, 512);
  gemm_kernel<0><<<dim3(12, 256), 256, 0, stream>>>(x, wqkv_t, qb, kb, vb, nullptr, nullptr);
  kv_partial_kernel<<<dim3(16, 32), 256, 0, stream>>>(kb, vb, part);
  kv_reduce_kernel<<<640, 256, 0, stream>>>(part, kv_ext);
  attn_kernel<<<dim3(32, 32), 256, 0, stream>>>(qb, kv_ext, vb);
  gemm_kernel<1><<<dim3(4, 256), 256, 0, stream>>>(vb, wout_t, nullptr, nullptr, nullptr, out, bout);
}

// Round 2
// 182.659 us; speedup vs baseline: 1.1521x; 1.1521x over previous
//
#include <hip/hip_runtime.h>

typedef unsigned short u16;
typedef __bf16 bf16x8 __attribute__((ext_vector_type(8)));
typedef float f32x4 __attribute__((ext_vector_type(4)));

#define DEV static __device__ __forceinline__

DEV float bf2f(u16 u) { unsigned x = ((unsigned)u) << 16; return __builtin_bit_cast(float, x); }
DEV u16 f2bf(float f) {
  unsigned u = __builtin_bit_cast(unsigned, f);
  u += 0x7FFFu + ((u >> 16) & 1u);
  return (u16)(u >> 16);
}

#define GLD_LDS16(gp, lp)                                                    \
  __builtin_amdgcn_global_load_lds(                                          \
      (__attribute__((address_space(1))) void*)(void*)(gp),                  \
      (__attribute__((address_space(3))) void*)(lp), 16, 0, 0)

// ---------------------------------------------------------------------------
// fp32 -> bf16 bulk convert (8 elems/thread, fully vectorized)
// ---------------------------------------------------------------------------
__global__ __launch_bounds__(256) void convert_bf16_kernel(
    const float* __restrict__ in, u16* __restrict__ out) {
  const size_t i = (size_t)blockIdx.x * 256 + threadIdx.x;
  const float4* p = (const float4*)in + 2 * i;
  float4 a = p[0], b = p[1];
  unsigned w0 = (unsigned)f2bf(a.x) | ((unsigned)f2bf(a.y) << 16);
  unsigned w1 = (unsigned)f2bf(a.z) | ((unsigned)f2bf(a.w) << 16);
  unsigned w2 = (unsigned)f2bf(b.x) | ((unsigned)f2bf(b.y) << 16);
  unsigned w3 = (unsigned)f2bf(b.z) | ((unsigned)f2bf(b.w) << 16);
  ((uint4*)out)[i] = make_uint4(w0, w1, w2, w3);
}

// ---------------------------------------------------------------------------
// Transpose + fp32->bf16 convert:  W[K][Ncols] -> Wt[Ncols][K]
// ---------------------------------------------------------------------------
__global__ void transpose_bf16(const float* __restrict__ W, u16* __restrict__ Wt,
                               int K, int Ncols) {
  __shared__ float t[32][33];
  const int tx = threadIdx.x & 31, ty = threadIdx.x >> 5;  // 32 x 8
  const int n0 = blockIdx.x * 32, k0 = blockIdx.y * 32;
#pragma unroll
  for (int i = 0; i < 4; ++i)
    t[ty + i * 8][tx] = W[(size_t)(k0 + ty + i * 8) * Ncols + n0 + tx];
  __syncthreads();
#pragma unroll
  for (int i = 0; i < 4; ++i)
    Wt[(size_t)(n0 + ty + i * 8) * K + k0 + tx] = f2bf(t[tx][ty + i * 8]);
}

// ---------------------------------------------------------------------------
// GEMM, 128x128 tile, BK=32, 4 waves (2x2), mfma_f32_16x16x32_bf16.
// Both operands bf16 [rows][512], staged via global_load_lds width-16.
// 1D grid with bijective XCD swizzle (nwg % 8 == 0).
// MODE 0: NX=12 col-tiles; epilogue elu+1 on cols<1024 -> q/k/v bf16 bufs.
// MODE 1: NX=4  col-tiles; epilogue + bias -> fp32 Cf.
// ---------------------------------------------------------------------------
template <int MODE>
__global__ __launch_bounds__(256, 2) void gemm_kernel(
    const u16* __restrict__ A, const u16* __restrict__ Bt,
    u16* __restrict__ qb, u16* __restrict__ kb, u16* __restrict__ vb,
    float* __restrict__ Cf, const float* __restrict__ bias) {
  constexpr int NX = (MODE == 0) ? 12 : 4;
  constexpr int BK = 32;
  constexpr int K = 512;
  __shared__ __align__(16) u16 As[128 * BK];
  __shared__ __align__(16) u16 Bs[128 * BK];
  const int tid = threadIdx.x;
  const int lane = tid & 63;
  const int wid = tid >> 6;
  const int wr = wid >> 1, wc = wid & 1;

  // XCD-aware swizzle: physical block p -> logical tile id; contiguous logical
  // range per XCD so the 12(/4) col-tiles of one A row-panel share one L2.
  const int nwg = gridDim.x;
  const int p = blockIdx.x;
  const int logical = (p & 7) * (nwg >> 3) + (p >> 3);
  const int rowBase = (logical / NX) * 128;
  const int colBase = (logical % NX) * 128;

  f32x4 zv = {0.f, 0.f, 0.f, 0.f};
  f32x4 acc[4][4];
#pragma unroll
  for (int m = 0; m < 4; ++m)
#pragma unroll
    for (int n = 0; n < 4; ++n) acc[m][n] = zv;

  for (int k0 = 0; k0 < K; k0 += BK) {
#pragma unroll
    for (int rr = 0; rr < 2; ++rr) {
      int idx8 = rr * 256 + tid;
      int r = idx8 >> 2, c = (idx8 & 3) * 8;
      GLD_LDS16(A + (size_t)(rowBase + r) * K + k0 + c,
                &As[(rr * 256 + wid * 64) * 8]);
    }
#pragma unroll
    for (int rr = 0; rr < 2; ++rr) {
      int idx8 = rr * 256 + tid;
      int r = idx8 >> 2, c = (idx8 & 3) * 8;
      GLD_LDS16(Bt + (size_t)(colBase + r) * K + k0 + c,
                &Bs[(rr * 256 + wid * 64) * 8]);
    }
    __syncthreads();

    bf16x8 af[4], bfr[4];
#pragma unroll
    for (int m = 0; m < 4; ++m)
      af[m] = *(const bf16x8*)&As[(wr * 64 + m * 16 + (lane & 15)) * BK + (lane >> 4) * 8];
#pragma unroll
    for (int n = 0; n < 4; ++n)
      bfr[n] = *(const bf16x8*)&Bs[(wc * 64 + n * 16 + (lane & 15)) * BK + (lane >> 4) * 8];
#pragma unroll
    for (int m = 0; m < 4; ++m)
#pragma unroll
      for (int n = 0; n < 4; ++n)
        acc[m][n] = __builtin_amdgcn_mfma_f32_16x16x32_bf16(af[m], bfr[n], acc[m][n], 0, 0, 0);
    __syncthreads();
  }

  // ---- epilogue
#pragma unroll
  for (int m = 0; m < 4; ++m) {
#pragma unroll
    for (int n = 0; n < 4; ++n) {
      const int col = colBase + wc * 64 + n * 16 + (lane & 15);
#pragma unroll
      for (int r = 0; r < 4; ++r) {
        const int row = rowBase + wr * 64 + m * 16 + (lane >> 4) * 4 + r;
        float v = acc[m][n][r];
        if (MODE == 0) {
          if (col < 1024) v = (v > 0.f) ? v + 1.f : __expf(v);  // elu(v)+1
          u16* dst;
          int c2;
          if (col < 512) {
            dst = qb; c2 = col;
          } else if (col < 1024) {
            dst = kb; c2 = col - 512;
          } else {
            dst = vb; c2 = col - 1024;
          }
          dst[(size_t)row * 512 + c2] = f2bf(v);
        } else {
          Cf[(size_t)row * 512 + col] = v + bias[col];
        }
      }
    }
  }
}

// ---------------------------------------------------------------------------
// kv partials: per (bh, chunk of 512 rows), acc[d][e] += k[n][d]*v[n][e],
// ksum[d] += k[n][d].  Output part[bh][chunk][64][80] (col 64 = ksum).
// ---------------------------------------------------------------------------
__global__ __launch_bounds__(256, 2) void kv_partial_kernel(
    const u16* __restrict__ kb, const u16* __restrict__ vb,
    float* __restrict__ part) {
  __shared__ float kf[128][64];
  __shared__ float vf[128][64];
  const int tid = threadIdx.x;
  const int chunk = blockIdx.x;  // 0..15 (512 rows each)
  const int bh = blockIdx.y;     // 0..31
  const int b = bh >> 3, h = bh & 7;
  const size_t rb = (size_t)b * 8192;
  const int hc = h * 64;
  const int dg = tid >> 4, eg = tid & 15;

  float acc[4][4] = {};
  float ks[4] = {};

  for (int st = 0; st < 4; ++st) {
    const int n0 = chunk * 512 + st * 128;
#pragma unroll
    for (int it = 0; it < 4; ++it) {
      int idx8 = it * 256 + tid;
      int r = idx8 >> 3, c = (idx8 & 7) * 8;
      uint4 kraw = *(const uint4*)(kb + (rb + n0 + r) * 512 + hc + c);
      uint4 vraw = *(const uint4*)(vb + (rb + n0 + r) * 512 + hc + c);
      unsigned kw[4] = {kraw.x, kraw.y, kraw.z, kraw.w};
      unsigned vw[4] = {vraw.x, vraw.y, vraw.z, vraw.w};
#pragma unroll
      for (int j = 0; j < 4; ++j) {
        kf[r][c + 2 * j] = bf2f((u16)(kw[j] & 0xFFFF));
        kf[r][c + 2 * j + 1] = bf2f((u16)(kw[j] >> 16));
        vf[r][c + 2 * j] = bf2f((u16)(vw[j] & 0xFFFF));
        vf[r][c + 2 * j + 1] = bf2f((u16)(vw[j] >> 16));
      }
    }
    __syncthreads();
#pragma unroll 4
    for (int n = 0; n < 128; ++n) {
      float4 kk = *(const float4*)&kf[n][dg * 4];
      float4 vv = *(const float4*)&vf[n][eg * 4];
      float ka[4] = {kk.x, kk.y, kk.z, kk.w};
      float va[4] = {vv.x, vv.y, vv.z, vv.w};
#pragma unroll
      for (int i = 0; i < 4; ++i)
#pragma unroll
        for (int j = 0; j < 4; ++j) acc[i][j] += ka[i] * va[j];
      if (eg == 0) {
#pragma unroll
        for (int i = 0; i < 4; ++i) ks[i] += ka[i];
      }
    }
    __syncthreads();
  }

  float* pp = part + ((size_t)bh * 16 + chunk) * (64 * 80);
#pragma unroll
  for (int i = 0; i < 4; ++i) {
#pragma unroll
    for (int j = 0; j < 4; ++j) pp[(dg * 4 + i) * 80 + eg * 4 + j] = acc[i][j];
    if (eg == 0) pp[(dg * 4 + i) * 80 + 64] = ks[i];
  }
}

// ---------------------------------------------------------------------------
// Reduce partials over chunks -> kv_ext[bh][64][80]; cols 65..79 zeroed.
// ---------------------------------------------------------------------------
__global__ void kv_reduce_kernel(const float* __restrict__ part,
                                 float* __restrict__ kv_ext) {
  const int idx = blockIdx.x * 256 + threadIdx.x;  // 32*5120 total
  const int bh = idx / 5120;
  const int de = idx % 5120;
  const int e = de % 80;
  float s = 0.f;
  if (e <= 64) {
    for (int c = 0; c < 16; ++c) s += part[((size_t)bh * 16 + c) * 5120 + de];
  }
  kv_ext[idx] = s;
}

// ---------------------------------------------------------------------------
// attn[n][h*64+e] = (sum_d q[n][d]*kv[d][e]) / (sum_d q[n][d]*ksum[d] + 1e-6)
// kv_ext col 64 = ksum -> denominator comes from a 5th MFMA e-block.
// ---------------------------------------------------------------------------
__global__ __launch_bounds__(256, 2) void attn_kernel(
    const u16* __restrict__ qb, const float* __restrict__ kv_ext,
    u16* __restrict__ attn) {
  __shared__ __align__(16) float kvs[64 * 80];   // 20 KB
  __shared__ __align__(16) u16 qs[4][64 * 64];   // 32 KB
  const int tid = threadIdx.x, lane = tid & 63, wid = tid >> 6;
  const int nchunk = blockIdx.x, bh = blockIdx.y;
  const int b = bh >> 3, h = bh & 7;

#pragma unroll
  for (int i = 0; i < 20; ++i)
    kvs[i * 256 + tid] = kv_ext[(size_t)bh * 5120 + i * 256 + tid];
  __syncthreads();

  // B fragments: B[d][e] = kvs[d*80+e], 5 e-blocks x 2 k-steps (one-time)
  bf16x8 bfr[5][2];
#pragma unroll
  for (int eb = 0; eb < 5; ++eb)
#pragma unroll
    for (int ksi = 0; ksi < 2; ++ksi) {
      unsigned pw[4];
#pragma unroll
      for (int jj = 0; jj < 4; ++jj) {
        int d0 = ksi * 32 + (lane >> 4) * 8 + 2 * jj;
        int e = eb * 16 + (lane & 15);
        unsigned lo = f2bf(kvs[d0 * 80 + e]);
        unsigned hi = f2bf(kvs[(d0 + 1) * 80 + e]);
        pw[jj] = lo | (hi << 16);
      }
      uint4 u = make_uint4(pw[0], pw[1], pw[2], pw[3]);
      bfr[eb][ksi] = __builtin_bit_cast(bf16x8, u);
    }

  // stage this wave's 64 q rows
  const size_t row0 = (size_t)b * 8192 + (size_t)nchunk * 256 + wid * 64;
#pragma unroll
  for (int it = 0; it < 8; ++it) {
    int idx8 = it * 64 + lane;
    int r = idx8 >> 3, c = (idx8 & 7) * 8;
    GLD_LDS16(qb + (row0 + r) * 512 + h * 64 + c, &qs[wid][it * 512]);
  }
  asm volatile("s_waitcnt vmcnt(0)" ::: "memory");

  f32x4 zv = {0.f, 0.f, 0.f, 0.f};
  f32x4 acc[4][5];
#pragma unroll
  for (int m = 0; m < 4; ++m)
#pragma unroll
    for (int eb = 0; eb < 5; ++eb) acc[m][eb] = zv;

#pragma unroll
  for (int m = 0; m < 4; ++m)
#pragma unroll
    for (int ksi = 0; ksi < 2; ++ksi) {
      bf16x8 af = *(const bf16x8*)&qs[wid][(m * 16 + (lane & 15)) * 64 + ksi * 32 + (lane >> 4) * 8];
#pragma unroll
      for (int eb = 0; eb < 5; ++eb)
        acc[m][eb] = __builtin_amdgcn_mfma_f32_16x16x32_bf16(af, bfr[eb][ksi], acc[m][eb], 0, 0, 0);
    }

#pragma unroll
  for (int m = 0; m < 4; ++m) {
    float zr[4];
#pragma unroll
    for (int r = 0; r < 4; ++r) {
      float den = __shfl(acc[m][4][r], lane & ~15, 64);
      zr[r] = 1.f / (den + 1e-6f);
    }
#pragma unroll
    for (int eb = 0; eb < 4; ++eb)
#pragma unroll
      for (int r = 0; r < 4; ++r) {
        size_t row = row0 + m * 16 + (lane >> 4) * 4 + r;
        int col = h * 64 + eb * 16 + (lane & 15);
        attn[row * 512 + col] = f2bf(acc[m][eb][r] * zr[r]);
      }
  }
}

// ---------------------------------------------------------------------------
extern "C" void kernel_launch(void* const* d_in, const int* in_sizes, int n_in,
                              void* d_out, int out_size, void* d_ws, size_t ws_size,
                              hipStream_t stream) {
  const float* x = (const float*)d_in[0];
  const float* Wqkv = (const float*)d_in[1];
  const float* Wout = (const float*)d_in[2];
  const float* bout = (const float*)d_in[3];
  float* out = (float*)d_out;

  char* ws = (char*)d_ws;
  u16* qb = (u16*)ws;        ws += (size_t)32768 * 512 * 2;
  u16* kb = (u16*)ws;        ws += (size_t)32768 * 512 * 2;
  u16* vb = (u16*)ws;        ws += (size_t)32768 * 512 * 2;  // reused as attn
  u16* wqkv_t = (u16*)ws;    ws += (size_t)1536 * 512 * 2;
  u16* wout_t = (u16*)ws;    ws += (size_t)512 * 512 * 2;
  float* kv_ext = (float*)ws; ws += (size_t)32 * 64 * 80 * 4;
  float* part = (float*)ws;   ws += (size_t)32 * 16 * 64 * 80 * 4;

  // x (bf16) lives in d_out: dead before GEMM2 overwrites d_out with the
  // final result (GEMM2 reads only vb/wout_t/bout).
  u16* xb = (u16*)d_out;

  convert_bf16_kernel<<<8192, 256, 0, stream>>>(x, xb);
  transpose_bf16<<<dim3(1536 / 32, 512 / 32), 256, 0, stream>>>(Wqkv, wqkv_t, 512, 1536);
  transpose_bf16<<<dim3(512 / 32, 512 / 32), 256, 0, stream>>>(Wout, wout_t, 512, 512);
  gemm_kernel<0><<<12 * 256, 256, 0, stream>>>(xb, wqkv_t, qb, kb, vb, nullptr, nullptr);
  kv_partial_kernel<<<dim3(16, 32), 256, 0, stream>>>(kb, vb, part);
  kv_reduce_kernel<<<640, 256, 0, stream>>>(part, kv_ext);
  attn_kernel<<<dim3(32, 32), 256, 0, stream>>>(qb, kv_ext, vb);
  gemm_kernel<1><<<4 * 256, 256, 0, stream>>>(vb, wout_t, nullptr, nullptr, nullptr, out, bout);
}

// Round 3
// 169.454 us; speedup vs baseline: 1.2419x; 1.0779x over previous
//
#include <hip/hip_runtime.h>

typedef unsigned short u16;
typedef __bf16 bf16x8 __attribute__((ext_vector_type(8)));
typedef float f32x4 __attribute__((ext_vector_type(4)));

#define DEV static __device__ __forceinline__

DEV float bf2f(u16 u) { unsigned x = ((unsigned)u) << 16; return __builtin_bit_cast(float, x); }
DEV u16 f2bf(float f) {
  unsigned u = __builtin_bit_cast(unsigned, f);
  u += 0x7FFFu + ((u >> 16) & 1u);
  return (u16)(u >> 16);
}

#define GLD_LDS16(gp, lp)                                                    \
  __builtin_amdgcn_global_load_lds(                                          \
      (__attribute__((address_space(1))) void*)(void*)(gp),                  \
      (__attribute__((address_space(3))) void*)(lp), 16, 0, 0)

#define BAR() __builtin_amdgcn_s_barrier()
#define WAIT_LGKM0()                                                         \
  { asm volatile("s_waitcnt lgkmcnt(0)" ::: "memory");                       \
    __builtin_amdgcn_sched_barrier(0); }
#define WAIT_VM(n) asm volatile("s_waitcnt vmcnt(" #n ")" ::: "memory")

// ---------------------------------------------------------------------------
// fp32 -> bf16 bulk convert (8 elems/thread)
// ---------------------------------------------------------------------------
__global__ __launch_bounds__(256) void convert_bf16_kernel(
    const float* __restrict__ in, u16* __restrict__ out) {
  const size_t i = (size_t)blockIdx.x * 256 + threadIdx.x;
  const float4* p = (const float4*)in + 2 * i;
  float4 a = p[0], b = p[1];
  unsigned w0 = (unsigned)f2bf(a.x) | ((unsigned)f2bf(a.y) << 16);
  unsigned w1 = (unsigned)f2bf(a.z) | ((unsigned)f2bf(a.w) << 16);
  unsigned w2 = (unsigned)f2bf(b.x) | ((unsigned)f2bf(b.y) << 16);
  unsigned w3 = (unsigned)f2bf(b.z) | ((unsigned)f2bf(b.w) << 16);
  ((uint4*)out)[i] = make_uint4(w0, w1, w2, w3);
}

// ---------------------------------------------------------------------------
// Transpose + fp32->bf16 convert:  W[K][Ncols] -> Wt[Ncols][K]
// ---------------------------------------------------------------------------
__global__ void transpose_bf16(const float* __restrict__ W, u16* __restrict__ Wt,
                               int K, int Ncols) {
  __shared__ float t[32][33];
  const int tx = threadIdx.x & 31, ty = threadIdx.x >> 5;  // 32 x 8
  const int n0 = blockIdx.x * 32, k0 = blockIdx.y * 32;
#pragma unroll
  for (int i = 0; i < 4; ++i)
    t[ty + i * 8][tx] = W[(size_t)(k0 + ty + i * 8) * Ncols + n0 + tx];
  __syncthreads();
#pragma unroll
  for (int i = 0; i < 4; ++i)
    Wt[(size_t)(n0 + ty + i * 8) * K + k0 + tx] = f2bf(t[tx][ty + i * 8]);
}

// ---------------------------------------------------------------------------
// 256x256 8-phase GEMM (T2+T3+T4+T5), BK=64, K=512 (8 K-tiles), 512 thr.
// A [M][512] bf16, Bt [N][512] bf16 (both row-major with K contiguous).
// LDS: As/Bs[parity][half][128*64], linear dest for global_load_lds with
// inverse-swizzled per-lane SOURCE; ds_read applies XOR (row&7)<<4.
// MODE 0: NX=6, epilogue elu+1 -> q/k/v bf16.  MODE 1: NX=2, +bias -> fp32.
// ---------------------------------------------------------------------------
template <int MODE>
__global__ __launch_bounds__(512, 2) void gemm8_kernel(
    const u16* __restrict__ A, const u16* __restrict__ Bt,
    u16* __restrict__ qb, u16* __restrict__ kb, u16* __restrict__ vb,
    float* __restrict__ Cf, const float* __restrict__ bias) {
  constexpr int NX = (MODE == 0) ? 6 : 2;
  constexpr int K = 512;
  __shared__ __align__(16) u16 As[2][2][8192];  // 64 KB
  __shared__ __align__(16) u16 Bs[2][2][8192];  // 64 KB

  const int tid = threadIdx.x;
  const int lane = tid & 63;
  const int wid = tid >> 6;   // 0..7
  const int wr = wid >> 2;    // 0..1  (M)
  const int wcn = wid & 3;    // 0..3  (N)

  const int nwg = gridDim.x;
  const int pb = blockIdx.x;
  const int logical = (pb & 7) * (nwg >> 3) + (pb >> 3);
  const int rowBase = (logical / NX) * 256;
  const int colBase = (logical % NX) * 256;

  // staging: per-lane inverse-swizzled source offsets (2 instrs/wave/half)
  int soff[2], od[2];
#pragma unroll
  for (int i = 0; i < 2; ++i) {
    int o = (wid * 2 + i) * 1024 + lane * 16;        // linear dest byte
    int a = o ^ (((o >> 7) & 7) << 4);               // swizzled source coord
    soff[i] = (a >> 7) * K + ((a & 127) >> 1);       // element offset in panel
    od[i] = (wid * 2 + i) * 512;                     // dest base (elements)
  }
  const u16* Abase = A + (size_t)rowBase * K;
  const u16* Bbase = Bt + (size_t)colBase * K;

#define STAGE_A(tau, h)                                                      \
  { const u16* g = Abase + (size_t)(h)*128 * K + (tau)*64;                   \
    _Pragma("unroll") for (int i = 0; i < 2; ++i)                            \
        GLD_LDS16(g + soff[i], &As[(tau)&1][h][od[i]]); }
#define STAGE_B(tau, h)                                                      \
  { const u16* g = Bbase + (size_t)(h)*128 * K + (tau)*64;                   \
    _Pragma("unroll") for (int i = 0; i < 2; ++i)                            \
        GLD_LDS16(g + soff[i], &Bs[(tau)&1][h][od[i]]); }

  // ds_read addressing: swizzled per-lane byte offsets
  const int sx = (lane & 7) << 4;
  int rb[2];
#pragma unroll
  for (int ks = 0; ks < 2; ++ks)
    rb[ks] = ((lane & 15) * 128 + ks * 64 + (lane >> 4) * 16) ^ sx;
  const char* Ahalf[2] = {(const char*)&As[0][wr][0], (const char*)&As[1][wr][0]};
  const char* Bhalf[2] = {(const char*)&Bs[0][wcn >> 1][0], (const char*)&Bs[1][wcn >> 1][0]};

  bf16x8 aA[4][2], bB0[2][2], bB1[2][2];
  f32x4 acc[8][4];
  f32x4 zv = {0.f, 0.f, 0.f, 0.f};
#pragma unroll
  for (int m = 0; m < 8; ++m)
#pragma unroll
    for (int n = 0; n < 4; ++n) acc[m][n] = zv;

#define LDA_FRAGS(par, mh)                                                   \
  _Pragma("unroll") for (int m = 0; m < 4; ++m)                              \
      _Pragma("unroll") for (int ks = 0; ks < 2; ++ks)                       \
          aA[m][ks] = *(const bf16x8*)(Ahalf[par] + (mh)*8192 + m * 2048 + rb[ks]);
#define LDB_FRAGS(par, nh, dst)                                              \
  _Pragma("unroll") for (int n = 0; n < 2; ++n)                              \
      _Pragma("unroll") for (int ks = 0; ks < 2; ++ks)                       \
          dst[n][ks] = *(const bf16x8*)(Bhalf[par] + (wcn & 1) * 8192 +      \
                                        (nh)*4096 + n * 2048 + rb[ks]);
#define MFMA_QUAD(mh, nh, bsrc)                                              \
  __builtin_amdgcn_s_setprio(1);                                             \
  _Pragma("unroll") for (int m = 0; m < 4; ++m)                              \
      _Pragma("unroll") for (int n = 0; n < 2; ++n)                          \
          _Pragma("unroll") for (int ks = 0; ks < 2; ++ks)                   \
              acc[(mh)*4 + m][(nh)*2 + n] =                                  \
                  __builtin_amdgcn_mfma_f32_16x16x32_bf16(                   \
                      aA[m][ks], bsrc[n][ks], acc[(mh)*4 + m][(nh)*2 + n],   \
                      0, 0, 0);                                              \
  __builtin_amdgcn_s_setprio(0);

  // ---- prologue: tile0 (4 halves) + B(1,0), A(1,0)
  STAGE_A(0, 0); STAGE_A(0, 1); STAGE_B(0, 0); STAGE_B(0, 1);
  STAGE_B(1, 0); STAGE_A(1, 0);
  WAIT_VM(4);   // tile0 resident; {B(1,0),A(1,0)} in flight
  BAR();

  // ---- main loop: pairs (0,1),(2,3),(4,5); even tile -> buf0, odd -> buf1
  for (int t = 0; t < 6; t += 2) {
    // ph1: tile t quad(0,0)
    LDA_FRAGS(0, 0); LDB_FRAGS(0, 0, bB0);
    STAGE_B(t + 1, 1);
    BAR(); WAIT_LGKM0();
    MFMA_QUAD(0, 0, bB0);
    BAR();
    // ph2: quad(0,1)
    LDB_FRAGS(0, 1, bB1);
    STAGE_A(t + 1, 1);
    BAR(); WAIT_LGKM0();
    MFMA_QUAD(0, 1, bB1);
    BAR();
    // ph3: quad(1,1)
    LDA_FRAGS(0, 1);
    STAGE_B(t + 2, 0);
    BAR(); WAIT_LGKM0();
    MFMA_QUAD(1, 1, bB1);
    BAR();
    // ph4: quad(1,0)   [tile t+1 must be fully drained here]
    STAGE_A(t + 2, 0);
    BAR(); WAIT_LGKM0();
    MFMA_QUAD(1, 0, bB0);
    WAIT_VM(4);
    BAR();
    // ph5: tile t+1 quad(0,0)
    LDA_FRAGS(1, 0); LDB_FRAGS(1, 0, bB0);
    STAGE_A(t + 2, 1);
    BAR(); WAIT_LGKM0();
    MFMA_QUAD(0, 0, bB0);
    BAR();
    // ph6: quad(0,1)
    LDB_FRAGS(1, 1, bB1);
    STAGE_B(t + 2, 1);
    BAR(); WAIT_LGKM0();
    MFMA_QUAD(0, 1, bB1);
    BAR();
    // ph7: quad(1,1)
    LDA_FRAGS(1, 1);
    STAGE_B(t + 3, 0);
    BAR(); WAIT_LGKM0();
    MFMA_QUAD(1, 1, bB1);
    BAR();
    // ph8: quad(1,0)   [tile t+2 must be fully drained here]
    STAGE_A(t + 3, 0);
    BAR(); WAIT_LGKM0();
    MFMA_QUAD(1, 0, bB0);
    WAIT_VM(4);
    BAR();
  }

  // ---- drain pair (6,7)
  // ph1
  LDA_FRAGS(0, 0); LDB_FRAGS(0, 0, bB0);
  STAGE_B(7, 1);
  BAR(); WAIT_LGKM0();
  MFMA_QUAD(0, 0, bB0);
  BAR();
  // ph2
  LDB_FRAGS(0, 1, bB1);
  STAGE_A(7, 1);
  BAR(); WAIT_LGKM0();
  MFMA_QUAD(0, 1, bB1);
  BAR();
  // ph3
  LDA_FRAGS(0, 1);
  BAR(); WAIT_LGKM0();
  MFMA_QUAD(1, 1, bB1);
  BAR();
  // ph4: drain everything (tile 7 resident after this)
  BAR(); WAIT_LGKM0();
  MFMA_QUAD(1, 0, bB0);
  WAIT_VM(0);
  BAR();
  // ph5..ph8: tile 7 (buf1)
  LDA_FRAGS(1, 0); LDB_FRAGS(1, 0, bB0);
  BAR(); WAIT_LGKM0();
  MFMA_QUAD(0, 0, bB0);
  BAR();
  LDB_FRAGS(1, 1, bB1);
  BAR(); WAIT_LGKM0();
  MFMA_QUAD(0, 1, bB1);
  BAR();
  LDA_FRAGS(1, 1);
  BAR(); WAIT_LGKM0();
  MFMA_QUAD(1, 1, bB1);
  BAR();
  BAR(); WAIT_LGKM0();
  MFMA_QUAD(1, 0, bB0);

  // ---- epilogue (regs only; no LDS)
  if (MODE == 0) {
    u16* dst = (colBase < 512) ? qb : (colBase < 1024) ? kb : vb;
    const int cb2 = (colBase < 512) ? colBase : (colBase < 1024) ? colBase - 512 : colBase - 1024;
    const bool doelu = (colBase < 1024);
#pragma unroll
    for (int mi = 0; mi < 8; ++mi) {
#pragma unroll
      for (int ni = 0; ni < 4; ++ni) {
        const int col = cb2 + wcn * 64 + ni * 16 + (lane & 15);
#pragma unroll
        for (int r = 0; r < 4; ++r) {
          const int row = rowBase + wr * 128 + mi * 16 + (lane >> 4) * 4 + r;
          float v = acc[mi][ni][r];
          if (doelu) v = (v > 0.f) ? v + 1.f : __expf(v);  // elu(v)+1
          dst[(size_t)row * 512 + col] = f2bf(v);
        }
      }
    }
  } else {
#pragma unroll
    for (int mi = 0; mi < 8; ++mi) {
#pragma unroll
      for (int ni = 0; ni < 4; ++ni) {
        const int col = colBase + wcn * 64 + ni * 16 + (lane & 15);
#pragma unroll
        for (int r = 0; r < 4; ++r) {
          const int row = rowBase + wr * 128 + mi * 16 + (lane >> 4) * 4 + r;
          Cf[(size_t)row * 512 + col] = acc[mi][ni][r] + bias[col];
        }
      }
    }
  }
#undef STAGE_A
#undef STAGE_B
#undef LDA_FRAGS
#undef LDB_FRAGS
#undef MFMA_QUAD
}

// ---------------------------------------------------------------------------
// kv partials: per (bh, chunk of 512 rows), acc[d][e] += k[n][d]*v[n][e],
// ksum[d] += k[n][d].  Output part[bh][chunk][64][80] (col 64 = ksum).
// ---------------------------------------------------------------------------
__global__ __launch_bounds__(256, 2) void kv_partial_kernel(
    const u16* __restrict__ kb, const u16* __restrict__ vb,
    float* __restrict__ part) {
  __shared__ float kf[128][64];
  __shared__ float vf[128][64];
  const int tid = threadIdx.x;
  const int chunk = blockIdx.x;  // 0..15
  const int bh = blockIdx.y;     // 0..31
  const int b = bh >> 3, h = bh & 7;
  const size_t rbase = (size_t)b * 8192;
  const int hc = h * 64;
  const int dg = tid >> 4, eg = tid & 15;

  float acc[4][4] = {};
  float ks[4] = {};

  for (int st = 0; st < 4; ++st) {
    const int n0 = chunk * 512 + st * 128;
#pragma unroll
    for (int it = 0; it < 4; ++it) {
      int idx8 = it * 256 + tid;
      int r = idx8 >> 3, c = (idx8 & 7) * 8;
      uint4 kraw = *(const uint4*)(kb + (rbase + n0 + r) * 512 + hc + c);
      uint4 vraw = *(const uint4*)(vb + (rbase + n0 + r) * 512 + hc + c);
      unsigned kw[4] = {kraw.x, kraw.y, kraw.z, kraw.w};
      unsigned vw[4] = {vraw.x, vraw.y, vraw.z, vraw.w};
#pragma unroll
      for (int j = 0; j < 4; ++j) {
        kf[r][c + 2 * j] = bf2f((u16)(kw[j] & 0xFFFF));
        kf[r][c + 2 * j + 1] = bf2f((u16)(kw[j] >> 16));
        vf[r][c + 2 * j] = bf2f((u16)(vw[j] & 0xFFFF));
        vf[r][c + 2 * j + 1] = bf2f((u16)(vw[j] >> 16));
      }
    }
    __syncthreads();
#pragma unroll 4
    for (int n = 0; n < 128; ++n) {
      float4 kk = *(const float4*)&kf[n][dg * 4];
      float4 vv = *(const float4*)&vf[n][eg * 4];
      float ka[4] = {kk.x, kk.y, kk.z, kk.w};
      float va[4] = {vv.x, vv.y, vv.z, vv.w};
#pragma unroll
      for (int i = 0; i < 4; ++i)
#pragma unroll
        for (int j = 0; j < 4; ++j) acc[i][j] += ka[i] * va[j];
      if (eg == 0) {
#pragma unroll
        for (int i = 0; i < 4; ++i) ks[i] += ka[i];
      }
    }
    __syncthreads();
  }

  float* pp = part + ((size_t)bh * 16 + chunk) * (64 * 80);
#pragma unroll
  for (int i = 0; i < 4; ++i) {
#pragma unroll
    for (int j = 0; j < 4; ++j) pp[(dg * 4 + i) * 80 + eg * 4 + j] = acc[i][j];
    if (eg == 0) pp[(dg * 4 + i) * 80 + 64] = ks[i];
  }
}

// ---------------------------------------------------------------------------
// Reduce partials over chunks -> kv_ext[bh][64][80]; cols 65..79 zeroed.
// ---------------------------------------------------------------------------
__global__ void kv_reduce_kernel(const float* __restrict__ part,
                                 float* __restrict__ kv_ext) {
  const int idx = blockIdx.x * 256 + threadIdx.x;  // 32*5120
  const int bh = idx / 5120;
  const int de = idx % 5120;
  const int e = de % 80;
  float s = 0.f;
  if (e <= 64) {
    for (int c = 0; c < 16; ++c) s += part[((size_t)bh * 16 + c) * 5120 + de];
  }
  kv_ext[idx] = s;
}

// ---------------------------------------------------------------------------
// attn[n][h*64+e] = (sum_d q[n][d]*kv[d][e]) / (sum_d q[n][d]*ksum[d] + 1e-6)
// ---------------------------------------------------------------------------
__global__ __launch_bounds__(256, 2) void attn_kernel(
    const u16* __restrict__ qb, const float* __restrict__ kv_ext,
    u16* __restrict__ attn) {
  __shared__ __align__(16) float kvs[64 * 80];
  __shared__ __align__(16) u16 qs[4][64 * 64];
  const int tid = threadIdx.x, lane = tid & 63, wid = tid >> 6;
  const int nchunk = blockIdx.x, bh = blockIdx.y;
  const int b = bh >> 3, h = bh & 7;

#pragma unroll
  for (int i = 0; i < 20; ++i)
    kvs[i * 256 + tid] = kv_ext[(size_t)bh * 5120 + i * 256 + tid];
  __syncthreads();

  bf16x8 bfr[5][2];
#pragma unroll
  for (int eb = 0; eb < 5; ++eb)
#pragma unroll
    for (int ksi = 0; ksi < 2; ++ksi) {
      unsigned pw[4];
#pragma unroll
      for (int jj = 0; jj < 4; ++jj) {
        int d0 = ksi * 32 + (lane >> 4) * 8 + 2 * jj;
        int e = eb * 16 + (lane & 15);
        unsigned lo = f2bf(kvs[d0 * 80 + e]);
        unsigned hi = f2bf(kvs[(d0 + 1) * 80 + e]);
        pw[jj] = lo | (hi << 16);
      }
      uint4 u = make_uint4(pw[0], pw[1], pw[2], pw[3]);
      bfr[eb][ksi] = __builtin_bit_cast(bf16x8, u);
    }

  const size_t row0 = (size_t)b * 8192 + (size_t)nchunk * 256 + wid * 64;
#pragma unroll
  for (int it = 0; it < 8; ++it) {
    int idx8 = it * 64 + lane;
    int r = idx8 >> 3, c = (idx8 & 7) * 8;
    GLD_LDS16(qb + (row0 + r) * 512 + h * 64 + c, &qs[wid][it * 512]);
  }
  asm volatile("s_waitcnt vmcnt(0)" ::: "memory");

  f32x4 zv = {0.f, 0.f, 0.f, 0.f};
  f32x4 acc[4][5];
#pragma unroll
  for (int m = 0; m < 4; ++m)
#pragma unroll
    for (int eb = 0; eb < 5; ++eb) acc[m][eb] = zv;

#pragma unroll
  for (int m = 0; m < 4; ++m)
#pragma unroll
    for (int ksi = 0; ksi < 2; ++ksi) {
      bf16x8 af = *(const bf16x8*)&qs[wid][(m * 16 + (lane & 15)) * 64 + ksi * 32 + (lane >> 4) * 8];
#pragma unroll
      for (int eb = 0; eb < 5; ++eb)
        acc[m][eb] = __builtin_amdgcn_mfma_f32_16x16x32_bf16(af, bfr[eb][ksi], acc[m][eb], 0, 0, 0);
    }

#pragma unroll
  for (int m = 0; m < 4; ++m) {
    float zr[4];
#pragma unroll
    for (int r = 0; r < 4; ++r) {
      float den = __shfl(acc[m][4][r], lane & ~15, 64);
      zr[r] = 1.f / (den + 1e-6f);
    }
#pragma unroll
    for (int eb = 0; eb < 4; ++eb)
#pragma unroll
      for (int r = 0; r < 4; ++r) {
        size_t row = row0 + m * 16 + (lane >> 4) * 4 + r;
        int col = h * 64 + eb * 16 + (lane & 15);
        attn[row * 512 + col] = f2bf(acc[m][eb][r] * zr[r]);
      }
  }
}

// ---------------------------------------------------------------------------
extern "C" void kernel_launch(void* const* d_in, const int* in_sizes, int n_in,
                              void* d_out, int out_size, void* d_ws, size_t ws_size,
                              hipStream_t stream) {
  const float* x = (const float*)d_in[0];
  const float* Wqkv = (const float*)d_in[1];
  const float* Wout = (const float*)d_in[2];
  const float* bout = (const float*)d_in[3];
  float* out = (float*)d_out;

  char* ws = (char*)d_ws;
  u16* qb = (u16*)ws;        ws += (size_t)32768 * 512 * 2;
  u16* kb = (u16*)ws;        ws += (size_t)32768 * 512 * 2;
  u16* vb = (u16*)ws;        ws += (size_t)32768 * 512 * 2;  // reused as attn
  u16* wqkv_t = (u16*)ws;    ws += (size_t)1536 * 512 * 2;
  u16* wout_t = (u16*)ws;    ws += (size_t)512 * 512 * 2;
  float* kv_ext = (float*)ws; ws += (size_t)32 * 64 * 80 * 4;
  float* part = (float*)ws;   ws += (size_t)32 * 16 * 64 * 80 * 4;

  // x (bf16) lives in d_out: dead before GEMM2 overwrites d_out.
  u16* xb = (u16*)d_out;

  convert_bf16_kernel<<<8192, 256, 0, stream>>>(x, xb);
  transpose_bf16<<<dim3(1536 / 32, 512 / 32), 256, 0, stream>>>(Wqkv, wqkv_t, 512, 1536);
  transpose_bf16<<<dim3(512 / 32, 512 / 32), 256, 0, stream>>>(Wout, wout_t, 512, 512);
  gemm8_kernel<0><<<768, 512, 0, stream>>>(xb, wqkv_t, qb, kb, vb, nullptr, nullptr);
  kv_partial_kernel<<<dim3(16, 32), 256, 0, stream>>>(kb, vb, part);
  kv_reduce_kernel<<<640, 256, 0, stream>>>(part, kv_ext);
  attn_kernel<<<dim3(32, 32), 256, 0, stream>>>(qb, kv_ext, vb);
  gemm8_kernel<1><<<256, 512, 0, stream>>>(vb, wout_t, nullptr, nullptr, nullptr, out, bout);
}